// Round 1
// baseline (421.037 us; speedup 1.0000x reference)
//
#include <hip/hip_runtime.h>

#define CC 85
#define NC 80
#define MAXGT 20
#define BSZ 64
#define IGNORE_T 0.5f
#define BT 512          /* threads per slot-block: 8 waves, 2/SIMD at 1 block/CU */
#define NWAVE (BT/64)

// ANCH_REV[l] = ANCHORS[2-l]
__constant__ float d_anch[3][3][2] = {
  {{0.2788f,0.2163f},{0.375f,0.476f},{0.8966f,0.7837f}},  // scale 0, lsz=13
  {{0.0721f,0.1466f},{0.149f,0.1082f},{0.1418f,0.2861f}}, // scale 1, lsz=26
  {{0.024f,0.0313f},{0.0385f,0.0721f},{0.0793f,0.0553f}}, // scale 2, lsz=52
};

__device__ __forceinline__ float sigmoidf(float x){ return 1.0f/(1.0f+__expf(-x)); }
__device__ __forceinline__ float bcef(float p, float t){
  p = fminf(fmaxf(p, 1e-7f), 1.0f-1e-7f);
  return -t*__logf(p) - (1.0f-t)*__logf(1.0f-p);
}

// All per-(scale,batch) state lives in LDS — no global header, no atomics,
// no memset. Each block owns exactly one slot and writes one float.
struct SlotSmem {
  int cnt;
  int pos[MAXGT];                       // GT row indices (scan order; order-invariant)
  int bn[MAXGT];                        // per-GT argmax row
  float gx[MAXGT], gy[MAXGT], gw[MAXGT], gh[MAXGT];
  float4 tb[MAXGT];                     // precomputed (tlx, tly, brx, bry)
  float area[MAXGT];
  unsigned long long lkey[NWAVE][MAXGT];
  float lnob[NWAVE];
  float lloss[NWAVE];
};

template<int LSZ, int S>
__device__ __forceinline__ void slot_loss(const float* __restrict__ pred,
                                          const float* __restrict__ tgt,
                                          float* __restrict__ out_slot,
                                          SlotSmem& sm)
{
  constexpr int L2 = LSZ*LSZ;
  constexpr int N  = 3*L2;
  const int tid = threadIdx.x;

  // ---- phase 1: conf scan (targets ~all-zero; <=20 hits). Scattered 64B
  // line per 340B row is unavoidable and cheaper than streaming all 85 ch.
  if (tid == 0) sm.cnt = 0;
  __syncthreads();
  for (int n = tid; n < N; n += BT) {
    if (tgt[(size_t)n*CC + 4] > 0.5f) {
      int i = atomicAdd(&sm.cnt, 1);          // LDS atomic
      if (i < MAXGT) sm.pos[i] = n;
    }
  }
  __syncthreads();
  const int G = min(sm.cnt, MAXGT);

  // ---- phase 2: GT boxes into LDS (fillers = zero box -> iou == 0 exactly,
  // matching the reference's gmask semantics)
  if (tid < MAXGT) {
    float x=0.f,y=0.f,w=0.f,h=0.f;
    if (tid < G) {
      const float* r = tgt + (size_t)sm.pos[tid]*CC;
      x=r[0]; y=r[1]; w=r[2]; h=r[3];
    }
    sm.gx[tid]=x; sm.gy[tid]=y; sm.gw[tid]=w; sm.gh[tid]=h;
    sm.tb[tid] = make_float4(x-w*0.5f, y-h*0.5f, x+w*0.5f, y+h*0.5f);
    sm.area[tid] = w*h;
  }
  __syncthreads();

  // ---- phase 3: decode + 20-way IoU argmax + noobj, 4-row register tile.
  // key[] must be fully static-indexed (all loops unrolled) to stay in VGPRs.
  unsigned long long key[MAXGT];
  #pragma unroll
  for (int g=0; g<MAXGT; g++) key[g]=0ull;
  float noobj = 0.0f;
  const float inv = 1.0f/(float)LSZ;

  for (int base = 0; base < N; base += BT*4) {
    float rx0[4],rx1[4],ry0[4],ry1[4],pa[4],q4v[4],maxi[4];
    int nr[4];
    #pragma unroll
    for (int r=0;r<4;r++){
      const int n = base + r*BT + tid;
      nr[r]=n; maxi[r]=0.f;
      if (n < N) {
        const int a = n/L2, rem = n - a*L2;
        const int ii = rem/LSZ, jj = rem - ii*LSZ;
        const float* bp = pred + (size_t)a*CC*L2 + rem;   // coalesced per channel
        const float q0=bp[0], q1=bp[L2], q2=bp[2*L2], q3=bp[3*L2];
        q4v[r]=bp[4*L2];
        const float px = ((float)jj + sigmoidf(q0))*inv;
        const float py = ((float)ii + sigmoidf(q1))*inv;
        const float pw = d_anch[S][a][0]*__expf(q2);
        const float ph = d_anch[S][a][1]*__expf(q3);
        rx0[r]=px-pw*0.5f; rx1[r]=px+pw*0.5f;
        ry0[r]=py-ph*0.5f; ry1[r]=py+ph*0.5f;
        pa[r]=pw*ph;
      } else {
        // zero box -> iou 0 for every GT; key contribution (0<<32)|~n can
        // never beat a valid row's key (valid n' < n implies ~n' > ~n)
        rx0[r]=0.f; rx1[r]=0.f; ry0[r]=0.f; ry1[r]=0.f; pa[r]=0.f; q4v[r]=0.f;
      }
    }
    #pragma unroll
    for (int g=0; g<MAXGT; g++){
      const float4 tb = sm.tb[g];          // broadcast ds_read_b128
      const float ga = sm.area[g];
      #pragma unroll
      for (int r=0;r<4;r++){
        const float w = fmaxf(fminf(tb.z,rx1[r]) - fmaxf(tb.x,rx0[r]), 0.0f);
        const float h = fmaxf(fminf(tb.w,ry1[r]) - fmaxf(tb.y,ry0[r]), 0.0f);
        const float inter = w*h;
        const float io = inter / fmaxf(ga + pa[r] - inter, 1e-6f);
        maxi[r] = fmaxf(maxi[r], io);
        const unsigned long long k =
          ((unsigned long long)__float_as_uint(io)<<32) |
          (unsigned long long)(~(unsigned)nr[r]);          // tie-break: first index
        if (k > key[g]) key[g] = k;
      }
    }
    #pragma unroll
    for (int r=0;r<4;r++)
      if (nr[r] < N && maxi[r] < IGNORE_T) noobj += bcef(sigmoidf(q4v[r]), 0.0f);
  }

  // ---- phase 4: block reduce keys + noobj (wave shfl -> LDS -> combine)
  const int wid = tid>>6, lane = tid&63;
  #pragma unroll
  for (int g=0; g<MAXGT; g++){
    unsigned long long k = key[g];
    for (int off=32; off>0; off>>=1){
      const unsigned long long o = __shfl_down(k, off, 64);
      if (o > k) k = o;
    }
    if (lane==0) sm.lkey[wid][g] = k;
  }
  for (int off=32; off>0; off>>=1) noobj += __shfl_down(noobj, off, 64);
  if (lane==0) sm.lnob[wid] = noobj;
  __syncthreads();
  if (tid < MAXGT){
    unsigned long long k = sm.lkey[0][tid];
    #pragma unroll
    for (int w=1; w<NWAVE; w++){ const unsigned long long o = sm.lkey[w][tid]; if (o>k) k=o; }
    sm.bn[tid] = (int)(~(unsigned)(k & 0xffffffffull));
  }
  __syncthreads();

  // ---- phase 5: reg/conf/cls losses + deduped noobj correction, same block
  float loss = 0.0f;
  if (tid < G){
    const int n = sm.bn[tid];
    const int a = n/L2, rem = n - a*L2, i = rem/LSZ, j = rem - i*LSZ;
    const float* bp = pred + (size_t)a*CC*L2 + rem;
    const float q0=bp[0], q1=bp[L2], q2=bp[2*L2], q3=bp[3*L2], q4=bp[4*L2];
    const float px = ((float)j + sigmoidf(q0))*inv;
    const float py = ((float)i + sigmoidf(q1))*inv;
    const float pw = d_anch[S][a][0]*__expf(q2);
    const float ph = d_anch[S][a][1]*__expf(q3);
    const float dx=px-sm.gx[tid], dy=py-sm.gy[tid], dw=pw-sm.gw[tid], dh=ph-sm.gh[tid];
    loss += (dx*dx+dy*dy+dw*dw+dh*dh)*(2.0f - sm.gw[tid]*sm.gh[tid]);  // reg
    loss += bcef(sigmoidf(q4), 1.0f);                                   // conf(obj)
    // subtract bce(conf,0) once per UNIQUE best index if it was counted in noobj
    bool first = true;
    for (int g2=0; g2<tid; g2++) if (sm.bn[g2]==n) first=false;
    if (first){
      float maxiou = 0.0f;
      const float bx0=px-pw*0.5f, bx1=px+pw*0.5f, by0=py-ph*0.5f, by1=py+ph*0.5f;
      const float parea=pw*ph;
      for (int g2=0; g2<MAXGT; g2++){
        const float4 tb = sm.tb[g2];
        const float w = fmaxf(fminf(tb.z,bx1) - fmaxf(tb.x,bx0), 0.0f);
        const float h = fmaxf(fminf(tb.w,by1) - fmaxf(tb.y,by0), 0.0f);
        const float inter = w*h;
        maxiou = fmaxf(maxiou, inter / fmaxf(sm.area[g2]+parea-inter, 1e-6f));
      }
      if (maxiou < IGNORE_T) loss -= bcef(sigmoidf(q4), 0.0f);
    }
  }
  // class loss: G*80 scattered gathers spread over 512 threads (~4 rounds)
  for (int idx = tid; idx < G*NC; idx += BT){
    const int g = idx/NC, c = idx - g*NC;
    const int n = sm.bn[g];
    const int a = n/L2, rem = n - a*L2;
    const float q  = pred[(size_t)a*CC*L2 + (size_t)(5+c)*L2 + rem];
    const float tc = tgt[(size_t)sm.pos[g]*CC + 5 + c];
    loss += bcef(sigmoidf(q), tc);
  }
  for (int off=32; off>0; off>>=1) loss += __shfl_down(loss, off, 64);
  if (lane==0) sm.lloss[wid] = loss;
  __syncthreads();
  if (tid==0){
    float v = 0.f;
    #pragma unroll
    for (int w=0; w<NWAVE; w++) v += sm.lloss[w] + sm.lnob[w];
    *out_slot = v;                    // unconditional store: poison-proof
  }
}

__global__ __launch_bounds__(BT, 2)
void k_fused(const float* __restrict__ p0, const float* __restrict__ t0,
             const float* __restrict__ p1, const float* __restrict__ t1,
             const float* __restrict__ p2, const float* __restrict__ t2,
             float* __restrict__ slot_out)
{
  __shared__ SlotSmem sm;
  const int b = blockIdx.x, s = blockIdx.y;
  float* o = slot_out + s*BSZ + b;
  if (s==0)      slot_loss<13,0>(p0 + (size_t)b*3*CC*13*13, t0 + (size_t)b*3*13*13*CC, o, sm);
  else if (s==1) slot_loss<26,1>(p1 + (size_t)b*3*CC*26*26, t1 + (size_t)b*3*26*26*CC, o, sm);
  else           slot_loss<52,2>(p2 + (size_t)b*3*CC*52*52, t2 + (size_t)b*3*52*52*CC, o, sm);
}

__global__ __launch_bounds__(256)
void k_sum(const float* __restrict__ slot_in, float* __restrict__ out)
{
  const int tid = threadIdx.x;
  float v = (tid < 3*BSZ) ? slot_in[tid] : 0.0f;
  for (int off=32; off>0; off>>=1) v += __shfl_down(v, off, 64);
  __shared__ float w[4];
  if ((tid&63)==0) w[tid>>6] = v;
  __syncthreads();
  if (tid==0) out[0] = w[0]+w[1]+w[2]+w[3];   // plain store: no d_out memset needed
}

extern "C" void kernel_launch(void* const* d_in, const int* in_sizes, int n_in,
                              void* d_out, int out_size, void* d_ws, size_t ws_size,
                              hipStream_t stream)
{
  // setup_inputs() dict order: pred0, targets0, pred1, targets1, pred2, targets2
  const float* p0 = (const float*)d_in[0];
  const float* t0 = (const float*)d_in[1];
  const float* p1 = (const float*)d_in[2];
  const float* t1 = (const float*)d_in[3];
  const float* p2 = (const float*)d_in[4];
  const float* t2 = (const float*)d_in[5];
  float* slot = (float*)d_ws;                 // 192 floats; fully rewritten each call

  k_fused<<<dim3(BSZ,3), BT, 0, stream>>>(p0,t0,p1,t1,p2,t2, slot);
  k_sum  <<<1, 256, 0, stream>>>(slot, (float*)d_out);
}

// Round 3
// 402.892 us; speedup vs baseline: 1.0450x; 1.0450x over previous
//
#include <hip/hip_runtime.h>

#define CC 85
#define NC 80
#define MAXGT 20
#define BSZ 64
#define IGNORE_T 0.5f
#define CHUNK 1024
#define NCHMAX 8

// rows per sample per scale: 3*lsz*lsz
#define N0 507
#define N1 2028
#define N2 8112
#define R0 (BSZ*N0)   /* 32448  */
#define R1 (BSZ*N1)   /* 129792 */
#define R2 (BSZ*N2)   /* 519168 */
#define RTOT (R0+R1+R2)

// ws layout (bytes). Only cnt needs zero-init (768 B memset). Everything
// else is written unconditionally before being read (poison-proof).
#define CNT_B    (192u*4u)                 /* int cnt[192]                  */
#define POS_OFF  CNT_B                     /* int pos[192][20]              */
#define POS_B    (192u*MAXGT*4u)
#define KEY_OFF  (POS_OFF+POS_B)           /* u64 keys[192][8][20], 8-align */
#define KEY_B    (192u*NCHMAX*MAXGT*8u)
#define NOB_OFF  (KEY_OFF+KEY_B)           /* float nob[192][8]             */
#define NOB_B    (192u*NCHMAX*4u)
#define PART_OFF (NOB_OFF+NOB_B)           /* float part[192][2]            */

// ANCH_REV[l] = ANCHORS[2-l]
__constant__ float d_anch[3][3][2] = {
  {{0.2788f,0.2163f},{0.375f,0.476f},{0.8966f,0.7837f}},  // scale 0, lsz=13
  {{0.0721f,0.1466f},{0.149f,0.1082f},{0.1418f,0.2861f}}, // scale 1, lsz=26
  {{0.024f,0.0313f},{0.0385f,0.0721f},{0.0793f,0.0553f}}, // scale 2, lsz=52
};

__device__ __forceinline__ float sigmoidf(float x){ return 1.0f/(1.0f+__expf(-x)); }
__device__ __forceinline__ float bcef(float p, float t){
  p = fminf(fmaxf(p, 1e-7f), 1.0f-1e-7f);
  return -t*__logf(p) - (1.0f-t)*__logf(1.0f-p);
}

// ---- kernel 0: conf scan only. 681K threads, 1 scattered 4B load each
// (one 64B line per 340B target row). ~10 waves/SIMD hides the latency.
template<int N>
__device__ __forceinline__ void scan_one(const float* __restrict__ tgt, int rl,
                                         int s, int* __restrict__ cnt,
                                         int* __restrict__ pos){
  int b = rl / N;                 // compile-time divisor
  int n = rl - b*N;
  if (tgt[(size_t)rl*CC + 4] > 0.5f){
    int slot = s*BSZ + b;
    int i = atomicAdd(&cnt[slot], 1);
    if (i < MAXGT) pos[slot*MAXGT + i] = n;
  }
}

__global__ __launch_bounds__(256)
void k_scan(const float* __restrict__ t0, const float* __restrict__ t1,
            const float* __restrict__ t2,
            int* __restrict__ cnt, int* __restrict__ pos){
  int r = blockIdx.x*256 + threadIdx.x;
  if (r < R0)         scan_one<N0>(t0, r,       0, cnt, pos);
  else if (r < R0+R1) scan_one<N1>(t1, r-R0,    1, cnt, pos);
  else if (r < RTOT)  scan_one<N2>(t2, r-R0-R1, 2, cnt, pos);
}

// ---- kernel 1: inline decode + 20-way IoU argmax keys + noobj per 1024-row
// chunk. No atomics: each chunk-block owns keys[slot][chunk][*], nob[slot][chunk].
// __launch_bounds__(256,2): key[20] (40 VGPR) must stay in registers.
template<int LSZ, int S>
__device__ __forceinline__ void iou_one(const float* __restrict__ pred,
                                        const float* __restrict__ tgt,
                                        int b, int chunk,
                                        const int* __restrict__ cnt,
                                        const int* __restrict__ pos,
                                        unsigned long long* __restrict__ keys,
                                        float* __restrict__ nob){
  constexpr int L2 = LSZ*LSZ, N = 3*L2;
  const int n0 = chunk*CHUNK;
  if (n0 >= N) return;                       // uniform per block
  const int slot = S*BSZ + b;
  const float* P = pred + (size_t)b*3*CC*L2;
  const float* T = tgt  + (size_t)b*N*CC;
  const int tid = threadIdx.x;
  __shared__ float4 tb[MAXGT];
  __shared__ float  area[MAXGT];
  __shared__ unsigned long long lkey[4][MAXGT];
  __shared__ float  lnob[4];
  if (tid < MAXGT){
    int G = min(cnt[slot], MAXGT);
    float x=0.f,y=0.f,w=0.f,h=0.f;
    if (tid < G){
      const float* r = T + (size_t)pos[slot*MAXGT+tid]*CC;
      x=r[0]; y=r[1]; w=r[2]; h=r[3];
    }
    tb[tid]   = make_float4(x-w*0.5f, y-h*0.5f, x+w*0.5f, y+h*0.5f);
    area[tid] = w*h;                         // zero box -> iou==0 (gmask filler)
  }
  __syncthreads();
  unsigned long long key[MAXGT];
  #pragma unroll
  for (int g=0; g<MAXGT; g++) key[g]=0ull;
  float noobj = 0.0f;
  const float inv = 1.0f/(float)LSZ;
  const int nend = min(n0+CHUNK, N);
  for (int n = n0+tid; n < nend; n += 256){
    const int a = n/L2, rem = n - a*L2, ii = rem/LSZ, jj = rem - ii*LSZ;
    const float* bp = P + (size_t)a*CC*L2 + rem;     // coalesced per channel
    const float q0=bp[0], q1=bp[L2], q2=bp[2*L2], q3=bp[3*L2], q4=bp[4*L2];
    const float px = ((float)jj + sigmoidf(q0))*inv;
    const float py = ((float)ii + sigmoidf(q1))*inv;
    const float pw = d_anch[S][a][0]*__expf(q2);
    const float ph = d_anch[S][a][1]*__expf(q3);
    const float x0=px-pw*0.5f, x1=px+pw*0.5f, y0=py-ph*0.5f, y1=py+ph*0.5f;
    const float pa = pw*ph;
    float maxi = 0.0f;
    const unsigned long long nin = (unsigned long long)(~(unsigned)n); // tie: first
    #pragma unroll
    for (int g=0; g<MAXGT; g++){
      const float4 t4 = tb[g];               // broadcast ds_read_b128
      const float w = fmaxf(fminf(t4.z,x1) - fmaxf(t4.x,x0), 0.0f);
      const float h = fmaxf(fminf(t4.w,y1) - fmaxf(t4.y,y0), 0.0f);
      const float inter = w*h;
      const float io = inter / fmaxf(area[g]+pa-inter, 1e-6f);
      maxi = fmaxf(maxi, io);
      const unsigned long long k =
        ((unsigned long long)__float_as_uint(io)<<32) | nin;
      if (k > key[g]) key[g] = k;
    }
    if (maxi < IGNORE_T) noobj += bcef(sigmoidf(q4), 0.0f);
  }
  const int wid = tid>>6, lane = tid&63;
  #pragma unroll
  for (int g=0; g<MAXGT; g++){
    unsigned long long k = key[g];
    for (int off=32; off>0; off>>=1){
      const unsigned long long o = __shfl_down(k, off, 64);
      if (o > k) k = o;
    }
    if (lane==0) lkey[wid][g] = k;
  }
  for (int off=32; off>0; off>>=1) noobj += __shfl_down(noobj, off, 64);
  if (lane==0) lnob[wid] = noobj;
  __syncthreads();
  if (tid < MAXGT){
    unsigned long long k = lkey[0][tid];
    #pragma unroll
    for (int w=1; w<4; w++){ const unsigned long long o = lkey[w][tid]; if (o>k) k=o; }
    keys[((size_t)slot*NCHMAX + chunk)*MAXGT + tid] = k;   // unconditional
  }
  if (tid==0) nob[slot*NCHMAX + chunk] = lnob[0]+lnob[1]+lnob[2]+lnob[3];
}

__global__ __launch_bounds__(256, 2)
void k_iou(const float* __restrict__ p0, const float* __restrict__ t0,
           const float* __restrict__ p1, const float* __restrict__ t1,
           const float* __restrict__ p2, const float* __restrict__ t2,
           const int* __restrict__ cnt, const int* __restrict__ pos,
           unsigned long long* __restrict__ keys, float* __restrict__ nob){
  const int chunk = blockIdx.x, b = blockIdx.y, s = blockIdx.z;
  if (s==0)      iou_one<13,0>(p0, t0, b, chunk, cnt, pos, keys, nob);
  else if (s==1) iou_one<26,1>(p1, t1, b, chunk, cnt, pos, keys, nob);
  else           iou_one<52,2>(p2, t2, b, chunk, cnt, pos, keys, nob);
}

// ---- kernel 2: chunk-max -> bn, then reg/conf/cls + deduped noobj
// correction. z-split x2 spreads the G*80 scattered class gathers.
template<int LSZ, int S, int NCH>
__device__ __forceinline__ void final_one(const float* __restrict__ pred,
                                          const float* __restrict__ tgt,
                                          int b, int z,
                                          const int* __restrict__ cnt,
                                          const int* __restrict__ pos,
                                          const unsigned long long* __restrict__ keys,
                                          const float* __restrict__ nob,
                                          float* __restrict__ part){
  constexpr int L2 = LSZ*LSZ, N = 3*L2;
  const int slot = S*BSZ + b;
  const float* P = pred + (size_t)b*3*CC*L2;
  const float* T = tgt  + (size_t)b*N*CC;
  const int tid = threadIdx.x;
  __shared__ int bn[MAXGT];
  __shared__ int gp[MAXGT];
  __shared__ float gx[MAXGT], gy[MAXGT], gw[MAXGT], gh[MAXGT];
  __shared__ float4 tb[MAXGT];
  __shared__ float area[MAXGT];
  const int G = min(cnt[slot], MAXGT);
  if (tid < MAXGT){
    unsigned long long k = keys[((size_t)slot*NCHMAX + 0)*MAXGT + tid];
    #pragma unroll
    for (int c=1; c<NCH; c++){
      const unsigned long long o = keys[((size_t)slot*NCHMAX + c)*MAXGT + tid];
      if (o > k) k = o;
    }
    bn[tid] = (int)(~(unsigned)(k & 0xffffffffull));
    float x=0.f,y=0.f,w=0.f,h=0.f; int p=0;
    if (tid < G){
      p = pos[slot*MAXGT + tid];
      const float* r = T + (size_t)p*CC;
      x=r[0]; y=r[1]; w=r[2]; h=r[3];
    }
    gp[tid]=p; gx[tid]=x; gy[tid]=y; gw[tid]=w; gh[tid]=h;
    tb[tid]   = make_float4(x-w*0.5f, y-h*0.5f, x+w*0.5f, y+h*0.5f);
    area[tid] = w*h;
  }
  __syncthreads();
  float loss = 0.0f;
  const float inv = 1.0f/(float)LSZ;
  if (z == 0 && tid < G){
    const int n = bn[tid];
    const int a = n/L2, rem = n - a*L2, i = rem/LSZ, j = rem - i*LSZ;
    const float* bp = P + (size_t)a*CC*L2 + rem;
    const float q0=bp[0], q1=bp[L2], q2=bp[2*L2], q3=bp[3*L2], q4=bp[4*L2];
    const float px = ((float)j + sigmoidf(q0))*inv;
    const float py = ((float)i + sigmoidf(q1))*inv;
    const float pw = d_anch[S][a][0]*__expf(q2);
    const float ph = d_anch[S][a][1]*__expf(q3);
    const float dx=px-gx[tid], dy=py-gy[tid], dw=pw-gw[tid], dh=ph-gh[tid];
    loss += (dx*dx+dy*dy+dw*dw+dh*dh)*(2.0f - gw[tid]*gh[tid]);  // reg
    loss += bcef(sigmoidf(q4), 1.0f);                             // conf(obj)
    // subtract bce(conf,0) once per UNIQUE best index if counted in noobj
    bool first = true;
    for (int g2=0; g2<tid; g2++) if (bn[g2]==n) first=false;
    if (first){
      const float bx0=px-pw*0.5f, bx1=px+pw*0.5f, by0=py-ph*0.5f, by1=py+ph*0.5f;
      const float parea = pw*ph;
      float maxiou = 0.0f;
      for (int g2=0; g2<MAXGT; g2++){
        const float4 t4 = tb[g2];
        const float w = fmaxf(fminf(t4.z,bx1) - fmaxf(t4.x,bx0), 0.0f);
        const float h = fmaxf(fminf(t4.w,by1) - fmaxf(t4.y,by0), 0.0f);
        const float inter = w*h;
        maxiou = fmaxf(maxiou, inter / fmaxf(area[g2]+parea-inter, 1e-6f));
      }
      if (maxiou < IGNORE_T) loss -= bcef(sigmoidf(q4), 0.0f);
    }
  }
  if (z == 0 && tid == 0){
    #pragma unroll
    for (int c=0; c<NCH; c++) loss += nob[slot*NCHMAX + c];
  }
  // class loss: G*80 scattered gathers interleaved across the 2 z-blocks
  for (int idx = z*256 + tid; idx < G*NC; idx += 512){
    const int g = idx/NC, c = idx - g*NC;
    const int n = bn[g];
    const int a = n/L2, rem = n - a*L2;
    const float q  = P[(size_t)a*CC*L2 + (size_t)(5+c)*L2 + rem];
    const float tc = T[(size_t)gp[g]*CC + 5 + c];
    loss += bcef(sigmoidf(q), tc);
  }
  __shared__ float wsum[4];
  for (int off=32; off>0; off>>=1) loss += __shfl_down(loss, off, 64);
  if ((tid&63)==0) wsum[tid>>6] = loss;
  __syncthreads();
  if (tid==0) part[slot*2 + z] = wsum[0]+wsum[1]+wsum[2]+wsum[3];  // unconditional
}

__global__ __launch_bounds__(256)
void k_final(const float* __restrict__ p0, const float* __restrict__ t0,
             const float* __restrict__ p1, const float* __restrict__ t1,
             const float* __restrict__ p2, const float* __restrict__ t2,
             const int* __restrict__ cnt, const int* __restrict__ pos,
             const unsigned long long* __restrict__ keys,
             const float* __restrict__ nob, float* __restrict__ part){
  const int b = blockIdx.x, s = blockIdx.y, z = blockIdx.z;
  if (s==0)      final_one<13,0,1>(p0, t0, b, z, cnt, pos, keys, nob, part);
  else if (s==1) final_one<26,1,2>(p1, t1, b, z, cnt, pos, keys, nob, part);
  else           final_one<52,2,8>(p2, t2, b, z, cnt, pos, keys, nob, part);
}

// ---- kernel 3: 384 partials -> out, plain store (no d_out memset needed)
__global__ __launch_bounds__(384)
void k_sum(const float* __restrict__ part, float* __restrict__ out){
  const int tid = threadIdx.x;
  float v = part[tid];
  for (int off=32; off>0; off>>=1) v += __shfl_down(v, off, 64);
  __shared__ float w[6];
  if ((tid&63)==0) w[tid>>6] = v;
  __syncthreads();
  if (tid==0){
    float s = 0.f;
    #pragma unroll
    for (int i=0; i<6; i++) s += w[i];
    out[0] = s;
  }
}

extern "C" void kernel_launch(void* const* d_in, const int* in_sizes, int n_in,
                              void* d_out, int out_size, void* d_ws, size_t ws_size,
                              hipStream_t stream)
{
  // setup_inputs() dict order: pred0, targets0, pred1, targets1, pred2, targets2
  const float* p0 = (const float*)d_in[0];
  const float* t0 = (const float*)d_in[1];
  const float* p1 = (const float*)d_in[2];
  const float* t1 = (const float*)d_in[3];
  const float* p2 = (const float*)d_in[4];
  const float* t2 = (const float*)d_in[5];
  char* ws = (char*)d_ws;
  int*                ws_cnt  = (int*)(ws);
  int*                ws_pos  = (int*)(ws + POS_OFF);
  unsigned long long* ws_keys = (unsigned long long*)(ws + KEY_OFF);
  float*              ws_nob  = (float*)(ws + NOB_OFF);
  float*              ws_part = (float*)(ws + PART_OFF);

  hipMemsetAsync(ws_cnt, 0, CNT_B, stream);          // only cnt needs zeroing

  k_scan <<<(RTOT+255)/256, 256, 0, stream>>>(t0,t1,t2, ws_cnt, ws_pos);
  k_iou  <<<dim3(NCHMAX,BSZ,3), 256, 0, stream>>>(p0,t0,p1,t1,p2,t2,
                                                  ws_cnt, ws_pos, ws_keys, ws_nob);
  k_final<<<dim3(BSZ,3,2), 256, 0, stream>>>(p0,t0,p1,t1,p2,t2,
                                             ws_cnt, ws_pos, ws_keys, ws_nob, ws_part);
  k_sum  <<<1, 384, 0, stream>>>(ws_part, (float*)d_out);
}